// Round 11
// baseline (291.471 us; speedup 1.0000x reference)
//
#include <hip/hip_runtime.h>
#include <math.h>

#define DIM 384
#define HEADS 6
#define HEAD_DIM 64
#define HIDDEN 1536
#define BATCH 8
#define SEQ 2048
#define TOKENS (BATCH * SEQ)

typedef __bf16 bf16;
typedef float f32x4 __attribute__((ext_vector_type(4)));
typedef float f32x16 __attribute__((ext_vector_type(16)));
typedef int i32x2 __attribute__((ext_vector_type(2)));
typedef int i32x4 __attribute__((ext_vector_type(4)));
typedef int i32x8 __attribute__((ext_vector_type(8)));

#define GLOAD_LDS(gp, lp)                                                      \
    __builtin_amdgcn_global_load_lds(                                          \
        (const __attribute__((address_space(1))) void*)(gp),                   \
        (__attribute__((address_space(3))) void*)(lp), 16, 0, 0)

__device__ __forceinline__ unsigned char to_fp8(float v) {
    return (unsigned char)(__builtin_amdgcn_cvt_pk_fp8_f32(v, v, 0, false) & 0xff);
}

__device__ __forceinline__ i32x8 pack8(i32x4 lo, i32x4 hi) {
    i32x8 r;
#pragma unroll
    for (int j = 0; j < 4; j++) { r[j] = lo[j]; r[4 + j] = hi[j]; }
    return r;
}

#define NW_QKV  (1152 * 384)
#define NW_PROJ (384 * 384)
#define NW_FC1  (1536 * 384)
#define NW_EYE  (1536 * 1536)
#define NW_FC2  (384 * 1536)
#define NW_ALL3 (NW_QKV + NW_PROJ + NW_FC1 + NW_FC2)

// ---------------- fp8 MX GEMM core (unit scales): C = A[M,K]f8 @ W[N,K]f8^T --
// EPI 0: plain -> fp8
// EPI 2: +bias, exact GELU -> fp8
// EPI 3: +bias, out_f32 = resid + v*gamma
// EPI 4: qkv: +bias; Q (scaled) + K -> fp8 qk8[tok][768]; V -> fp8 vtb8^T
template <int EPI>
__device__ __forceinline__ void gemm_core(const unsigned char* __restrict__ A,
                                          const unsigned char* __restrict__ W,
                                          const float* __restrict__ bias,
                                          float* __restrict__ outf,
                                          const float* __restrict__ resid,
                                          const float* __restrict__ gamma,
                                          unsigned char* __restrict__ vtb8,
                                          unsigned char* __restrict__ out8,
                                          int N, int K, int bx, int by,
                                          unsigned char* As, unsigned char* Bs) {
    int tid = threadIdx.x;
    int wave = tid >> 6, lane = tid & 63;
    int l15 = lane & 15, quad = lane >> 4;
    int bm = by * 128, bn = bx * 128;
    int wm = (wave & 1) * 64, wn = (wave >> 1) * 64;
    f32x4 acc[4][4] = {};

    for (int k0 = 0; k0 < K; k0 += 128) {
#pragma unroll
        for (int i = 0; i < 4; i++) {
            int slot = i * 256 + tid;            // 1024 chunks of 16B per tile
            int rr = slot >> 3;
            int gg = (slot & 7) ^ (rr & 7);
            GLOAD_LDS(A + (size_t)(bm + rr) * K + k0 + gg * 16,
                      (char*)As + (i * 256 + wave * 64) * 16);
            GLOAD_LDS(W + (size_t)(bn + rr) * K + k0 + gg * 16,
                      (char*)Bs + (i * 256 + wave * 64) * 16);
        }
        __syncthreads();
        i32x8 af[4], bfr[4];
#pragma unroll
        for (int mt = 0; mt < 4; mt++) {
            int rA = wm + mt * 16 + l15;
            const i32x4* p = (const i32x4*)(As + 128 * rA);
            af[mt] = pack8(p[(2 * quad) ^ (rA & 7)], p[(2 * quad + 1) ^ (rA & 7)]);
        }
#pragma unroll
        for (int nt = 0; nt < 4; nt++) {
            int rB = wn + nt * 16 + l15;
            const i32x4* p = (const i32x4*)(Bs + 128 * rB);
            bfr[nt] = pack8(p[(2 * quad) ^ (rB & 7)], p[(2 * quad + 1) ^ (rB & 7)]);
        }
#pragma unroll
        for (int mt = 0; mt < 4; mt++)
#pragma unroll
            for (int nt = 0; nt < 4; nt++)
                acc[mt][nt] = __builtin_amdgcn_mfma_scale_f32_16x16x128_f8f6f4(
                    af[mt], bfr[nt], acc[mt][nt], 0, 0,
                    0, 0x7f7f7f7f, 0, 0x7f7f7f7f);
        __syncthreads();
    }

#pragma unroll
    for (int mt = 0; mt < 4; mt++) {
#pragma unroll
        for (int nt = 0; nt < 4; nt++) {
            int col = bn + wn + nt * 16 + l15;
            int row0 = bm + wm + mt * 16 + quad * 4;
            float v[4];
#pragma unroll
            for (int r = 0; r < 4; r++) {
                v[r] = acc[mt][nt][r];
                if (EPI >= 2) v[r] += bias[col];
                if (EPI == 2) v[r] = 0.5f * v[r] * (1.f + erff(v[r] * 0.70710678118654752f));
            }
            if (EPI == 3) {
#pragma unroll
                for (int r = 0; r < 4; r++) {
                    size_t idx = (size_t)(row0 + r) * N + col;
                    outf[idx] = resid[idx] + v[r] * gamma[col];
                }
            } else if (EPI == 4) {
                if (col < 768) {  // wave-uniform per nt (boundary multiple of 16)
                    float sc = (col < 384) ? 0.180336880f : 1.f;  // 0.125*log2(e)
#pragma unroll
                    for (int r = 0; r < 4; r++)
                        out8[(size_t)(row0 + r) * 768 + col] = to_fp8(v[r] * sc);
                } else {
                    int hd = col - 768;
                    int b = row0 >> 11;
                    int n0 = row0 & 2047;
                    int p = __builtin_amdgcn_cvt_pk_fp8_f32(v[0], v[1], 0, false);
                    p = __builtin_amdgcn_cvt_pk_fp8_f32(v[2], v[3], p, true);
                    *(int*)(vtb8 + ((size_t)(b * 384 + hd) << 11) + n0) = p;
                }
            } else {
#pragma unroll
                for (int r = 0; r < 4; r++)
                    out8[(size_t)(row0 + r) * N + col] = to_fp8(v[r]);
            }
        }
    }
}

template <int EPI>
__global__ __launch_bounds__(256) void gemm_f8(const unsigned char* __restrict__ A,
                                               const unsigned char* __restrict__ W,
                                               const float* __restrict__ bias,
                                               float* __restrict__ outf,
                                               const float* __restrict__ resid,
                                               const float* __restrict__ gamma,
                                               unsigned char* __restrict__ vtb8,
                                               unsigned char* __restrict__ out8,
                                               int N, int K) {
    __shared__ __attribute__((aligned(16))) unsigned char As[128 * 128];
    __shared__ __attribute__((aligned(16))) unsigned char Bs[128 * 128];
    gemm_core<EPI>(A, W, bias, outf, resid, gamma, vtb8, out8, N, K,
                   blockIdx.x, blockIdx.y, As, Bs);
}

// ---------------- K1: ln1 + e1^T + e2^T + weight convert (block-range union) -
__global__ __launch_bounds__(256) void fused_pre(const float* __restrict__ x,
                                                 const float* __restrict__ n1w,
                                                 const float* __restrict__ n1b,
                                                 unsigned char* __restrict__ hbuf8,
                                                 const float* __restrict__ e1,
                                                 unsigned char* __restrict__ e1t8,
                                                 const float* __restrict__ e2,
                                                 unsigned char* __restrict__ e2t8,
                                                 const float* __restrict__ qkv,
                                                 const float* __restrict__ proj,
                                                 const float* __restrict__ fc1,
                                                 const float* __restrict__ fc2,
                                                 unsigned char* __restrict__ w8,
                                                 int* __restrict__ flag) {
    __shared__ float tb[64][65];
    int bid = blockIdx.x;
    int tid = threadIdx.x;
    if (bid == 0 && tid == 0) *flag = 0;   // reset dependency counter for K2
    if (bid < 4096) {
        // ---- ln1: 4 tokens/block, one wave per token ----
        int wave = tid >> 6, lane = tid & 63;
        int tok = bid * 4 + wave;
        const float* xr = x + (size_t)tok * DIM;
        float v[6];
        float s = 0.f;
#pragma unroll
        for (int i = 0; i < 6; i++) { v[i] = xr[lane + 64 * i]; s += v[i]; }
#pragma unroll
        for (int m = 1; m < 64; m <<= 1) s += __shfl_xor(s, m, 64);
        float mu = s * (1.f / DIM);
        float q = 0.f;
#pragma unroll
        for (int i = 0; i < 6; i++) { float d = v[i] - mu; q += d * d; }
#pragma unroll
        for (int m = 1; m < 64; m <<= 1) q += __shfl_xor(q, m, 64);
        float rstd = rsqrtf(q * (1.f / DIM) + 1e-5f);
        unsigned char* orow = hbuf8 + (size_t)tok * DIM;
#pragma unroll
        for (int i = 0; i < 6; i++) {
            int c = lane + 64 * i;
            orow[c] = to_fp8((v[i] - mu) * rstd * n1w[c] + n1b[c]);
        }
    } else if (bid < 5248) {
        // ---- eN fp32 [1536][1536] -> eN^T fp8 (e1: bids 4096..4671, e2: ..5247)
        int g = bid - 4096;
        const float* src = e1;
        unsigned char* dst = e1t8;
        if (g >= 576) { g -= 576; src = e2; dst = e2t8; }
        int r0 = (g / 24) * 64, c0 = (g % 24) * 64;
        int tc = tid & 63, tr = tid >> 6;
#pragma unroll
        for (int i = 0; i < 16; i++) {
            int r = tr + 4 * i;
            tb[r][tc] = src[(size_t)(r0 + r) * 1536 + c0 + tc];
        }
        __syncthreads();
        int on = tid >> 2;
        int ok0 = (tid & 3) * 16;
        i32x4 pk;
#pragma unroll
        for (int q = 0; q < 4; q++) {
            int p = __builtin_amdgcn_cvt_pk_fp8_f32(tb[ok0 + 4 * q + 0][on],
                                                    tb[ok0 + 4 * q + 1][on], 0, false);
            p = __builtin_amdgcn_cvt_pk_fp8_f32(tb[ok0 + 4 * q + 2][on],
                                                tb[ok0 + 4 * q + 3][on], p, true);
            pk[q] = p;
        }
        *(i32x4*)(dst + (size_t)(c0 + on) * 1536 + r0 + ok0) = pk;
    } else {
        // ---- convert qkv/proj/fc1/fc2 fp32 -> fp8 (1728 blocks, exact) ----
        int q4 = (bid - 5248) * 256 + tid;
        int i = q4 * 4;
        int j = i;
        const float* src;
        if (j < NW_QKV) src = qkv;
        else if ((j -= NW_QKV) < NW_PROJ) src = proj;
        else if ((j -= NW_PROJ) < NW_FC1) src = fc1;
        else { j -= NW_FC1; src = fc2; }
        float4 v = *(const float4*)(src + j);
        int p = __builtin_amdgcn_cvt_pk_fp8_f32(v.x, v.y, 0, false);
        p = __builtin_amdgcn_cvt_pk_fp8_f32(v.z, v.w, p, true);
        *(int*)(w8 + i) = p;
    }
}

// ---------------- K2: prep1 (bids 0-35) + qkv GEMM + prep2 (bids 1188-1223) --
// prep2 depends on prep1's output (wfe8): in-kernel flag chain. prep1 blocks
// release-increment `flag` after storing F; prep2 blocks (scheduled last)
// acquire-poll until flag==36. Deadlock-free: only 36 blocks ever spin, so
// they cannot exhaust CU capacity needed to schedule prep1. Both preps hide
// in qkv's idle slots (1152 blocks = 4.5/CU; attn hosting cost 12us, R10).
__global__ __launch_bounds__(256) void gemm_qkv_prep(const unsigned char* __restrict__ hbuf8,
                                                     const unsigned char* __restrict__ wqkv8,
                                                     const float* __restrict__ qkv_b,
                                                     unsigned char* __restrict__ vtb8,
                                                     unsigned char* __restrict__ qk8,
                                                     const unsigned char* __restrict__ wfc28,
                                                     const unsigned char* __restrict__ e2t8,
                                                     unsigned char* wfe8,
                                                     const unsigned char* __restrict__ e1t8,
                                                     unsigned char* wc8,
                                                     int* flag) {
    __shared__ __attribute__((aligned(16))) unsigned char As[128 * 128];
    __shared__ __attribute__((aligned(16))) unsigned char Bs[128 * 128];
    int bid = blockIdx.x;
    int tid = threadIdx.x;
    if (bid < 36) {
        // F[384,1536] = fc2 @ e2 = A(wfc28) @ (e2^T)^T, K=1536
        gemm_core<0>(wfc28, e2t8, nullptr, nullptr, nullptr, nullptr, nullptr, wfe8,
                     1536, 1536, bid % 12, bid / 12, As, Bs);
        __threadfence();          // flush this thread's F stores to device scope
        __syncthreads();          // all threads in block have fenced
        if (tid == 0)
            __hip_atomic_fetch_add(flag, 1, __ATOMIC_RELEASE, __HIP_MEMORY_SCOPE_AGENT);
    } else if (bid < 36 + 1152) {
        int g = bid - 36;
        gemm_core<4>(hbuf8, wqkv8, qkv_b, nullptr, nullptr, nullptr, vtb8, qk8,
                     1152, 384, g % 9, g / 9, As, Bs);
    } else {
        // prep2: wait for all 36 prep1 blocks, then Wc[384,1536] = F @ e1
        if (tid == 0) {
            while (__hip_atomic_load(flag, __ATOMIC_ACQUIRE, __HIP_MEMORY_SCOPE_AGENT) < 36)
                __builtin_amdgcn_s_sleep(8);
        }
        __syncthreads();
        __threadfence();
        int g = bid - (36 + 1152);
        gemm_core<0>(wfe8, e1t8, nullptr, nullptr, nullptr, nullptr, nullptr, wc8,
                     1536, 1536, g % 12, g / 12, As, Bs);
    }
}

// ---------------- K4: proj GEMM + residual + ls1 + LayerNorm2 (pure) ---------
__global__ __launch_bounds__(256) void gemm_projln(const unsigned char* __restrict__ A,
                                                   const unsigned char* __restrict__ W,
                                                   const float* __restrict__ bias,
                                                   const float* __restrict__ resid,
                                                   const float* __restrict__ gamma,
                                                   const float* __restrict__ n2w,
                                                   const float* __restrict__ n2b,
                                                   float* __restrict__ x1,
                                                   unsigned char* __restrict__ hbuf8) {
    __shared__ __attribute__((aligned(16))) unsigned char As[64 * 128];
    __shared__ __attribute__((aligned(16))) unsigned char Bs[384 * 128];
    int tid = threadIdx.x;
    int wave = tid >> 6, lane = tid & 63;
    int l15 = lane & 15, quad = lane >> 4;
    int bm = blockIdx.x * 64;
    int wm = wave * 16;
    f32x4 acc[24];
#pragma unroll
    for (int i = 0; i < 24; i++) acc[i] = (f32x4){0.f, 0.f, 0.f, 0.f};

    const int K = 384;
    for (int k0 = 0; k0 < K; k0 += 128) {
#pragma unroll
        for (int i = 0; i < 2; i++) {
            int slot = i * 256 + tid;
            int rr = slot >> 3, gg = (slot & 7) ^ (rr & 7);
            GLOAD_LDS(A + (size_t)(bm + rr) * K + k0 + gg * 16, (char*)As + slot * 16);
        }
#pragma unroll
        for (int i = 0; i < 12; i++) {
            int slot = i * 256 + tid;
            int rr = slot >> 3, gg = (slot & 7) ^ (rr & 7);
            GLOAD_LDS(W + (size_t)rr * K + k0 + gg * 16, (char*)Bs + slot * 16);
        }
        __syncthreads();
        int rA = wm + l15;
        const i32x4* pa = (const i32x4*)(As + 128 * rA);
        i32x8 af = pack8(pa[(2 * quad) ^ (rA & 7)], pa[(2 * quad + 1) ^ (rA & 7)]);
#pragma unroll
        for (int nt = 0; nt < 24; nt++) {
            int rB = nt * 16 + l15;
            const i32x4* pb = (const i32x4*)(Bs + 128 * rB);
            i32x8 bf = pack8(pb[(2 * quad) ^ (rB & 7)], pb[(2 * quad + 1) ^ (rB & 7)]);
            acc[nt] = __builtin_amdgcn_mfma_scale_f32_16x16x128_f8f6f4(
                af, bf, acc[nt], 0, 0, 0, 0x7f7f7f7f, 0, 0x7f7f7f7f);
        }
        __syncthreads();
    }

    int row0 = bm + wm + quad * 4;
#pragma unroll
    for (int nt = 0; nt < 24; nt++) {
        int col = nt * 16 + l15;
        float bi = bias[col], ga = gamma[col];
#pragma unroll
        for (int r = 0; r < 4; r++) {
            size_t idx = (size_t)(row0 + r) * DIM + col;
            float v = resid[idx] + (acc[nt][r] + bi) * ga;
            x1[idx] = v;
            acc[nt][r] = v;
        }
    }
#pragma unroll
    for (int r = 0; r < 4; r++) {
        float s = 0.f;
#pragma unroll
        for (int nt = 0; nt < 24; nt++) s += acc[nt][r];
#pragma unroll
        for (int m = 1; m < 16; m <<= 1) s += __shfl_xor(s, m, 64);
        float mu = s * (1.f / DIM);
        float q = 0.f;
#pragma unroll
        for (int nt = 0; nt < 24; nt++) { float d = acc[nt][r] - mu; q += d * d; }
#pragma unroll
        for (int m = 1; m < 16; m <<= 1) q += __shfl_xor(q, m, 64);
        float rstd = rsqrtf(q * (1.f / DIM) + 1e-5f);
        unsigned char* orow = hbuf8 + (size_t)(row0 + r) * DIM;
#pragma unroll
        for (int nt = 0; nt < 24; nt++) {
            int col = nt * 16 + l15;
            orow[col] = to_fp8((acc[nt][r] - mu) * rstd * n2w[col] + n2b[col]);
        }
    }
}

// ---------------- K3: flash attention, fp8 32x32x64, KVBLK=128 (pure) --------
// 16 iters; 4 waves x 32 Q-rows; LDS 32 KB; 3 blocks/CU; VGPR ~56.
__global__ __launch_bounds__(256, 3) void attn_kernel(const unsigned char* __restrict__ qk8,
                                                      const unsigned char* __restrict__ vtb8,
                                                      unsigned char* __restrict__ o) {
    __shared__ __attribute__((aligned(16))) unsigned char Ks[2][128 * 64];
    __shared__ __attribute__((aligned(16))) unsigned char Vts[2][64 * 128];
    int tid = threadIdx.x, wave = tid >> 6, lane = tid & 63;
    int l31 = lane & 31, h = lane >> 5;
    int bh = blockIdx.y;
    int b = bh / HEADS, hh = bh - b * HEADS;
    int qr0 = blockIdx.x * 128 + wave * 32;
    const unsigned char* base = qk8 + (size_t)b * SEQ * 768;
    const unsigned char* vbase = vtb8 + ((size_t)bh << 17);  // bh*64*2048

    int kr0 = tid >> 2, kr1 = (tid + 256) >> 2, ks = tid & 3;
    const unsigned char* kg0 = base + (size_t)kr0 * 768 + 384 + hh * 64 + 16 * (ks ^ ((kr0 >> 1) & 3));
    const unsigned char* kg1 = base + (size_t)kr1 * 768 + 384 + hh * 64 + 16 * (ks ^ ((kr1 >> 1) & 3));
    int vr0 = tid >> 3, vr1 = (tid + 256) >> 3, vs = tid & 7;
    const unsigned char* vg0 = vbase + ((size_t)vr0 << 11) + 16 * (vs ^ ((vr0 >> 1) & 3));
    const unsigned char* vg1 = vbase + ((size_t)vr1 << 11) + 16 * (vs ^ ((vr1 >> 1) & 3));
    int lo0 = tid * 16, lo1 = (tid + 256) * 16;

    i32x8 aq = *(const i32x8*)(base + (size_t)(qr0 + l31) * 768 + hh * 64 + 32 * h);

    f32x16 oa0 = {}, oa1 = {};
    float lsum = 0.f;
    int swr = (l31 >> 1) & 3;

    GLOAD_LDS(kg0, (char*)Ks[0] + lo0);
    GLOAD_LDS(kg1, (char*)Ks[0] + lo1);
    GLOAD_LDS(vg0, (char*)Vts[0] + lo0);
    GLOAD_LDS(vg1, (char*)Vts[0] + lo1);
    __syncthreads();

    for (int kt = 0; kt < SEQ / 128; kt++) {
        const unsigned char* Kc = Ks[kt & 1];
        const unsigned char* Vc = Vts[kt & 1];
        if (kt + 1 < SEQ / 128) {
            char* kn = (char*)Ks[(kt + 1) & 1];
            char* vn = (char*)Vts[(kt + 1) & 1];
            size_t kadv = (size_t)(kt + 1) * 128 * 768;
            int vadv = (kt + 1) * 128;
            GLOAD_LDS(kg0 + kadv, kn + lo0);
            GLOAD_LDS(kg1 + kadv, kn + lo1);
            GLOAD_LDS(vg0 + vadv, vn + lo0);
            GLOAD_LDS(vg1 + vadv, vn + lo1);
        }

        int pk[4][4];
#pragma unroll
        for (int mi = 0; mi < 4; mi++) {
            int rK = 32 * mi + l31;
            const i32x4* kp = (const i32x4*)(Kc + rK * 64);
            i32x8 ak = pack8(kp[(2 * h + 0) ^ swr], kp[(2 * h + 1) ^ swr]);
            f32x16 s = {};
            s = __builtin_amdgcn_mfma_scale_f32_32x32x64_f8f6f4(
                ak, aq, s, 0, 0, 0, 0x7f7f7f7f, 0, 0x7f7f7f7f);
#pragma unroll
            for (int g = 0; g < 4; g++) {
                float p0 = __builtin_amdgcn_exp2f(s[4 * g + 0]);
                float p1 = __builtin_amdgcn_exp2f(s[4 * g + 1]);
                float p2 = __builtin_amdgcn_exp2f(s[4 * g + 2]);
                float p3 = __builtin_amdgcn_exp2f(s[4 * g + 3]);
                lsum += (p0 + p1) + (p2 + p3);
                int pkv = __builtin_amdgcn_cvt_pk_fp8_f32(p0, p1, 0, false);
                pkv = __builtin_amdgcn_cvt_pk_fp8_f32(p2, p3, pkv, true);
                pk[mi][g] = pkv;
            }
        }

        i32x8 ap0, ap1;
#pragma unroll
        for (int g = 0; g < 4; g++) {
            i32x2 r0 = __builtin_amdgcn_permlane32_swap(pk[0][g], pk[1][g], false, false);
            ap0[2 * g] = r0[0];
            ap0[2 * g + 1] = r0[1];
            i32x2 r1 = __builtin_amdgcn_permlane32_swap(pk[2][g], pk[3][g], false, false);
            ap1[2 * g] = r1[0];
            ap1[2 * g + 1] = r1[1];
        }

        {
            const i32x4* vp0 = (const i32x4*)(Vc + l31 * 128);
            const i32x4* vp1 = (const i32x4*)(Vc + (32 + l31) * 128);
            i32x8 bv00 = pack8(vp0[(2 * h + 0) ^ swr], vp0[(2 * h + 1) ^ swr]);
            i32x8 bv01 = pack8(vp0[4 + ((2 * h + 0) ^ swr)], vp0[4 + ((2 * h + 1) ^ swr)]);
            i32x8 bv10 = pack8(vp1[(2 * h + 0) ^ swr], vp1[(2 * h + 1) ^ swr]);
            i32x8 bv11 = pack8(vp1[4 + ((2 * h + 0) ^ swr)], vp1[4 + ((2 * h + 1) ^ swr)]);
            oa0 = __builtin_amdgcn_mfma_scale_f32_32x32x64_f8f6f4(
                ap0, bv00, oa0, 0, 0, 0, 0x7f7f7f7f, 0, 0x7f7f7f7f);
            oa0 = __builtin_amdgcn_mfma_scale_f32_32x32x64_f8f6f4(
                ap1, bv01, oa0, 0, 0, 0, 0x7f7f7f7f, 0, 0x7f7f7f7f);
            oa1 = __builtin_amdgcn_mfma_scale_f32_32x32x64_f8f6f4(
                ap0, bv10, oa1, 0, 0, 0, 0x7f7f7f7f, 0, 0x7f7f7f7f);
            oa1 = __builtin_amdgcn_mfma_scale_f32_32x32x64_f8f6f4(
                ap1, bv11, oa1, 0, 0, 0, 0x7f7f7f7f, 0, 0x7f7f7f7f);
        }
        __syncthreads();
    }

    lsum += __shfl_xor(lsum, 32, 64);

#pragma unroll
    for (int g = 0; g < 4; g++) {
#pragma unroll
        for (int r4 = 0; r4 < 4; r4++) {
            int qloc = r4 + 8 * g + 4 * h;
            float inv = 1.f / __shfl(lsum, qloc, 64);
            int r = 4 * g + r4;
            unsigned char* orow = o + ((size_t)(b * SEQ + qr0 + qloc)) * DIM + hh * 64;
            orow[l31]      = to_fp8(oa0[r] * inv);
            orow[32 + l31] = to_fp8(oa1[r] * inv);
        }
    }
}

// ---------------- orchestration ----------------------------------------------
extern "C" void kernel_launch(void* const* d_in, const int* in_sizes, int n_in,
                              void* d_out, int out_size, void* d_ws, size_t ws_size,
                              hipStream_t stream) {
    const float* x      = (const float*)d_in[0];
    const float* qkv_w  = (const float*)d_in[1];
    const float* qkv_b  = (const float*)d_in[2];
    const float* proj_w = (const float*)d_in[3];
    const float* proj_b = (const float*)d_in[4];
    const float* fc1_w  = (const float*)d_in[5];
    const float* fc1_b  = (const float*)d_in[6];
    const float* eye1_w = (const float*)d_in[7];
    const float* eye2_w = (const float*)d_in[8];
    const float* fc2_w  = (const float*)d_in[9];
    const float* fc2_b  = (const float*)d_in[10];
    const float* n1w    = (const float*)d_in[11];
    const float* n1b    = (const float*)d_in[12];
    const float* n2w    = (const float*)d_in[13];
    const float* n2b    = (const float*)d_in[14];
    const float* ls1    = (const float*)d_in[15];
    const float* ls2    = (const float*)d_in[16];
    float* out = (float*)d_out;

    char* w = (char*)d_ws;
    size_t off = 0;
    unsigned char* w8 = (unsigned char*)(w + off); off += (size_t)NW_ALL3;
    unsigned char* wqkv8  = w8;
    unsigned char* wproj8 = wqkv8 + NW_QKV;
    unsigned char* wfc18  = wproj8 + NW_PROJ;
    unsigned char* wfc28  = wfc18 + NW_FC1;
    unsigned char* e1t8  = (unsigned char*)(w + off); off += (size_t)NW_EYE;
    unsigned char* e2t8  = (unsigned char*)(w + off); off += (size_t)NW_EYE;
    unsigned char* wfe8  = (unsigned char*)(w + off); off += (size_t)NW_FC2;
    unsigned char* wc8   = (unsigned char*)(w + off); off += (size_t)NW_FC2;
    unsigned char* hbuf8 = (unsigned char*)(w + off); off += (size_t)TOKENS * DIM;
    unsigned char* qk8   = (unsigned char*)(w + off); off += (size_t)TOKENS * 768;
    unsigned char* vtb8  = (unsigned char*)(w + off); off += (size_t)TOKENS * DIM;
    unsigned char* obuf8 = (unsigned char*)(w + off); off += (size_t)TOKENS * DIM;
    unsigned char* abuf8 = (unsigned char*)(w + off); off += (size_t)TOKENS * HIDDEN;
    float* x1   = (float*)(w + off); off += (size_t)TOKENS * DIM * 4;
    int* flag   = (int*)(w + off); off += 256;

    // K1: ln1 + e1^T + e2^T + weight convert (+ flag reset)
    fused_pre<<<4096 + 1152 + 1728, 256, 0, stream>>>(
        x, n1w, n1b, hbuf8, eye1_w, e1t8, eye2_w, e2t8,
        qkv_w, proj_w, fc1_w, fc2_w, w8, flag);

    // K2: prep1 (F=fc2@e2) + qkv GEMM + prep2 (Wc=F@e1, flag-chained)
    gemm_qkv_prep<<<36 + 1152 + 36, 256, 0, stream>>>(hbuf8, wqkv8, qkv_b, vtb8, qk8,
                                                      wfc28, e2t8, wfe8, e1t8, wc8, flag);

    // K3: attention (pure, KVBLK=128)
    attn_kernel<<<dim3(SEQ / 128, BATCH * HEADS), 256, 0, stream>>>(qk8, vtb8, obuf8);

    // K4: proj + resid + ls1 + LN2
    gemm_projln<<<TOKENS / 64, 256, 0, stream>>>(obuf8, wproj8, proj_b, x, ls1,
                                                 n2w, n2b, x1, hbuf8);

    // K5: fc1 + GELU
    gemm_f8<2><<<dim3(1536 / 128, TOKENS / 128), 256, 0, stream>>>(
        hbuf8, wfc18, fc1_b, nullptr, nullptr, nullptr, nullptr, abuf8, 1536, 384);

    // K6: y = a @ Wc^T + bias; out = x1 + y*ls2
    gemm_f8<3><<<dim3(384 / 128, TOKENS / 128), 256, 0, stream>>>(
        abuf8, wc8, fc2_b, out, x1, ls2, nullptr, nullptr, 384, 1536);
}

// Round 12
// 270.267 us; speedup vs baseline: 1.0785x; 1.0785x over previous
//
#include <hip/hip_runtime.h>
#include <math.h>

#define DIM 384
#define HEADS 6
#define HEAD_DIM 64
#define HIDDEN 1536
#define BATCH 8
#define SEQ 2048
#define TOKENS (BATCH * SEQ)

typedef __bf16 bf16;
typedef float f32x4 __attribute__((ext_vector_type(4)));
typedef float f32x16 __attribute__((ext_vector_type(16)));
typedef int i32x2 __attribute__((ext_vector_type(2)));
typedef int i32x4 __attribute__((ext_vector_type(4)));
typedef int i32x8 __attribute__((ext_vector_type(8)));

#define GLOAD_LDS(gp, lp)                                                      \
    __builtin_amdgcn_global_load_lds(                                          \
        (const __attribute__((address_space(1))) void*)(gp),                   \
        (__attribute__((address_space(3))) void*)(lp), 16, 0, 0)

__device__ __forceinline__ unsigned char to_fp8(float v) {
    return (unsigned char)(__builtin_amdgcn_cvt_pk_fp8_f32(v, v, 0, false) & 0xff);
}

__device__ __forceinline__ i32x8 pack8(i32x4 lo, i32x4 hi) {
    i32x8 r;
#pragma unroll
    for (int j = 0; j < 4; j++) { r[j] = lo[j]; r[4 + j] = hi[j]; }
    return r;
}

#define NW_QKV  (1152 * 384)
#define NW_PROJ (384 * 384)
#define NW_FC1  (1536 * 384)
#define NW_EYE  (1536 * 1536)
#define NW_FC2  (384 * 1536)
#define NW_ALL3 (NW_QKV + NW_PROJ + NW_FC1 + NW_FC2)

// ---------------- fp8 MX GEMM core (unit scales): C = A[M,K]f8 @ W[N,K]f8^T --
// EPI 0: plain -> fp8
// EPI 2: +bias, exact GELU -> fp8
// EPI 3: +bias, out_f32 = resid + v*gamma
// EPI 4: qkv: +bias; Q (scaled) + K -> fp8 qk8[tok][768]; V -> fp8 vtb8^T
template <int EPI>
__device__ __forceinline__ void gemm_core(const unsigned char* __restrict__ A,
                                          const unsigned char* __restrict__ W,
                                          const float* __restrict__ bias,
                                          float* __restrict__ outf,
                                          const float* __restrict__ resid,
                                          const float* __restrict__ gamma,
                                          unsigned char* __restrict__ vtb8,
                                          unsigned char* __restrict__ out8,
                                          int N, int K, int bx, int by,
                                          unsigned char* As, unsigned char* Bs) {
    int tid = threadIdx.x;
    int wave = tid >> 6, lane = tid & 63;
    int l15 = lane & 15, quad = lane >> 4;
    int bm = by * 128, bn = bx * 128;
    int wm = (wave & 1) * 64, wn = (wave >> 1) * 64;
    f32x4 acc[4][4] = {};

    for (int k0 = 0; k0 < K; k0 += 128) {
#pragma unroll
        for (int i = 0; i < 4; i++) {
            int slot = i * 256 + tid;            // 1024 chunks of 16B per tile
            int rr = slot >> 3;
            int gg = (slot & 7) ^ (rr & 7);
            GLOAD_LDS(A + (size_t)(bm + rr) * K + k0 + gg * 16,
                      (char*)As + (i * 256 + wave * 64) * 16);
            GLOAD_LDS(W + (size_t)(bn + rr) * K + k0 + gg * 16,
                      (char*)Bs + (i * 256 + wave * 64) * 16);
        }
        __syncthreads();
        i32x8 af[4], bfr[4];
#pragma unroll
        for (int mt = 0; mt < 4; mt++) {
            int rA = wm + mt * 16 + l15;
            const i32x4* p = (const i32x4*)(As + 128 * rA);
            af[mt] = pack8(p[(2 * quad) ^ (rA & 7)], p[(2 * quad + 1) ^ (rA & 7)]);
        }
#pragma unroll
        for (int nt = 0; nt < 4; nt++) {
            int rB = wn + nt * 16 + l15;
            const i32x4* p = (const i32x4*)(Bs + 128 * rB);
            bfr[nt] = pack8(p[(2 * quad) ^ (rB & 7)], p[(2 * quad + 1) ^ (rB & 7)]);
        }
#pragma unroll
        for (int mt = 0; mt < 4; mt++)
#pragma unroll
            for (int nt = 0; nt < 4; nt++)
                acc[mt][nt] = __builtin_amdgcn_mfma_scale_f32_16x16x128_f8f6f4(
                    af[mt], bfr[nt], acc[mt][nt], 0, 0,
                    0, 0x7f7f7f7f, 0, 0x7f7f7f7f);
        __syncthreads();
    }

#pragma unroll
    for (int mt = 0; mt < 4; mt++) {
#pragma unroll
        for (int nt = 0; nt < 4; nt++) {
            int col = bn + wn + nt * 16 + l15;
            int row0 = bm + wm + mt * 16 + quad * 4;
            float v[4];
#pragma unroll
            for (int r = 0; r < 4; r++) {
                v[r] = acc[mt][nt][r];
                if (EPI >= 2) v[r] += bias[col];
                if (EPI == 2) v[r] = 0.5f * v[r] * (1.f + erff(v[r] * 0.70710678118654752f));
            }
            if (EPI == 3) {
#pragma unroll
                for (int r = 0; r < 4; r++) {
                    size_t idx = (size_t)(row0 + r) * N + col;
                    outf[idx] = resid[idx] + v[r] * gamma[col];
                }
            } else if (EPI == 4) {
                if (col < 768) {  // wave-uniform per nt (boundary multiple of 16)
                    float sc = (col < 384) ? 0.180336880f : 1.f;  // 0.125*log2(e)
#pragma unroll
                    for (int r = 0; r < 4; r++)
                        out8[(size_t)(row0 + r) * 768 + col] = to_fp8(v[r] * sc);
                } else {
                    int hd = col - 768;
                    int b = row0 >> 11;
                    int n0 = row0 & 2047;
                    int p = __builtin_amdgcn_cvt_pk_fp8_f32(v[0], v[1], 0, false);
                    p = __builtin_amdgcn_cvt_pk_fp8_f32(v[2], v[3], p, true);
                    *(int*)(vtb8 + ((size_t)(b * 384 + hd) << 11) + n0) = p;
                }
            } else {
#pragma unroll
                for (int r = 0; r < 4; r++)
                    out8[(size_t)(row0 + r) * N + col] = to_fp8(v[r]);
            }
        }
    }
}

template <int EPI>
__global__ __launch_bounds__(256) void gemm_f8(const unsigned char* __restrict__ A,
                                               const unsigned char* __restrict__ W,
                                               const float* __restrict__ bias,
                                               float* __restrict__ outf,
                                               const float* __restrict__ resid,
                                               const float* __restrict__ gamma,
                                               unsigned char* __restrict__ vtb8,
                                               unsigned char* __restrict__ out8,
                                               int N, int K) {
    __shared__ __attribute__((aligned(16))) unsigned char As[128 * 128];
    __shared__ __attribute__((aligned(16))) unsigned char Bs[128 * 128];
    gemm_core<EPI>(A, W, bias, outf, resid, gamma, vtb8, out8, N, K,
                   blockIdx.x, blockIdx.y, As, Bs);
}

// ---------------- BM=64 variant (EPI=3 epilogue): balanced grid for fc2 ------
// fc2: N=384, grid 3 x 256 = 768 blocks = exactly 3/CU (was 384 = 1.5/CU ->
// 2:1 load imbalance, ~25% idle). LDS 24 KB. Same accumulation order ->
// bitwise-identical output.
__global__ __launch_bounds__(256) void gemm_f8_m64(const unsigned char* __restrict__ A,
                                                   const unsigned char* __restrict__ W,
                                                   const float* __restrict__ bias,
                                                   float* __restrict__ outf,
                                                   const float* __restrict__ resid,
                                                   const float* __restrict__ gamma,
                                                   int N, int K) {
    __shared__ __attribute__((aligned(16))) unsigned char As[64 * 128];
    __shared__ __attribute__((aligned(16))) unsigned char Bs[128 * 128];
    int tid = threadIdx.x;
    int wave = tid >> 6, lane = tid & 63;
    int l15 = lane & 15, quad = lane >> 4;
    int bm = blockIdx.y * 64, bn = blockIdx.x * 128;
    int wm = (wave & 1) * 32, wn = (wave >> 1) * 64;
    f32x4 acc[2][4] = {};

    for (int k0 = 0; k0 < K; k0 += 128) {
        // A: 64 rows x 8 chunks = 512 slots (2/thread); B: 1024 slots (4/thread)
#pragma unroll
        for (int i = 0; i < 2; i++) {
            int slot = i * 256 + tid;
            int rr = slot >> 3, gg = (slot & 7) ^ (rr & 7);
            GLOAD_LDS(A + (size_t)(bm + rr) * K + k0 + gg * 16,
                      (char*)As + (i * 256 + wave * 64) * 16);
        }
#pragma unroll
        for (int i = 0; i < 4; i++) {
            int slot = i * 256 + tid;
            int rr = slot >> 3, gg = (slot & 7) ^ (rr & 7);
            GLOAD_LDS(W + (size_t)(bn + rr) * K + k0 + gg * 16,
                      (char*)Bs + (i * 256 + wave * 64) * 16);
        }
        __syncthreads();
        i32x8 af[2], bfr[4];
#pragma unroll
        for (int mt = 0; mt < 2; mt++) {
            int rA = wm + mt * 16 + l15;
            const i32x4* p = (const i32x4*)(As + 128 * rA);
            af[mt] = pack8(p[(2 * quad) ^ (rA & 7)], p[(2 * quad + 1) ^ (rA & 7)]);
        }
#pragma unroll
        for (int nt = 0; nt < 4; nt++) {
            int rB = wn + nt * 16 + l15;
            const i32x4* p = (const i32x4*)(Bs + 128 * rB);
            bfr[nt] = pack8(p[(2 * quad) ^ (rB & 7)], p[(2 * quad + 1) ^ (rB & 7)]);
        }
#pragma unroll
        for (int mt = 0; mt < 2; mt++)
#pragma unroll
            for (int nt = 0; nt < 4; nt++)
                acc[mt][nt] = __builtin_amdgcn_mfma_scale_f32_16x16x128_f8f6f4(
                    af[mt], bfr[nt], acc[mt][nt], 0, 0,
                    0, 0x7f7f7f7f, 0, 0x7f7f7f7f);
        __syncthreads();
    }

#pragma unroll
    for (int mt = 0; mt < 2; mt++) {
#pragma unroll
        for (int nt = 0; nt < 4; nt++) {
            int col = bn + wn + nt * 16 + l15;
            int row0 = bm + wm + mt * 16 + quad * 4;
#pragma unroll
            for (int r = 0; r < 4; r++) {
                float v = acc[mt][nt][r] + bias[col];
                size_t idx = (size_t)(row0 + r) * N + col;
                outf[idx] = resid[idx] + v * gamma[col];
            }
        }
    }
}

// ---------------- K1: ln1 + e1^T + e2^T + weight convert (block-range union) -
__global__ __launch_bounds__(256) void fused_pre(const float* __restrict__ x,
                                                 const float* __restrict__ n1w,
                                                 const float* __restrict__ n1b,
                                                 unsigned char* __restrict__ hbuf8,
                                                 const float* __restrict__ e1,
                                                 unsigned char* __restrict__ e1t8,
                                                 const float* __restrict__ e2,
                                                 unsigned char* __restrict__ e2t8,
                                                 const float* __restrict__ qkv,
                                                 const float* __restrict__ proj,
                                                 const float* __restrict__ fc1,
                                                 const float* __restrict__ fc2,
                                                 unsigned char* __restrict__ w8) {
    __shared__ float tb[64][65];
    int bid = blockIdx.x;
    int tid = threadIdx.x;
    if (bid < 4096) {
        // ---- ln1: 4 tokens/block, one wave per token ----
        int wave = tid >> 6, lane = tid & 63;
        int tok = bid * 4 + wave;
        const float* xr = x + (size_t)tok * DIM;
        float v[6];
        float s = 0.f;
#pragma unroll
        for (int i = 0; i < 6; i++) { v[i] = xr[lane + 64 * i]; s += v[i]; }
#pragma unroll
        for (int m = 1; m < 64; m <<= 1) s += __shfl_xor(s, m, 64);
        float mu = s * (1.f / DIM);
        float q = 0.f;
#pragma unroll
        for (int i = 0; i < 6; i++) { float d = v[i] - mu; q += d * d; }
#pragma unroll
        for (int m = 1; m < 64; m <<= 1) q += __shfl_xor(q, m, 64);
        float rstd = rsqrtf(q * (1.f / DIM) + 1e-5f);
        unsigned char* orow = hbuf8 + (size_t)tok * DIM;
#pragma unroll
        for (int i = 0; i < 6; i++) {
            int c = lane + 64 * i;
            orow[c] = to_fp8((v[i] - mu) * rstd * n1w[c] + n1b[c]);
        }
    } else if (bid < 5248) {
        // ---- eN fp32 [1536][1536] -> eN^T fp8 (e1: bids 4096..4671, e2: ..5247)
        int g = bid - 4096;
        const float* src = e1;
        unsigned char* dst = e1t8;
        if (g >= 576) { g -= 576; src = e2; dst = e2t8; }
        int r0 = (g / 24) * 64, c0 = (g % 24) * 64;
        int tc = tid & 63, tr = tid >> 6;
#pragma unroll
        for (int i = 0; i < 16; i++) {
            int r = tr + 4 * i;
            tb[r][tc] = src[(size_t)(r0 + r) * 1536 + c0 + tc];
        }
        __syncthreads();
        int on = tid >> 2;
        int ok0 = (tid & 3) * 16;
        i32x4 pk;
#pragma unroll
        for (int q = 0; q < 4; q++) {
            int p = __builtin_amdgcn_cvt_pk_fp8_f32(tb[ok0 + 4 * q + 0][on],
                                                    tb[ok0 + 4 * q + 1][on], 0, false);
            p = __builtin_amdgcn_cvt_pk_fp8_f32(tb[ok0 + 4 * q + 2][on],
                                                tb[ok0 + 4 * q + 3][on], p, true);
            pk[q] = p;
        }
        *(i32x4*)(dst + (size_t)(c0 + on) * 1536 + r0 + ok0) = pk;
    } else {
        // ---- convert qkv/proj/fc1/fc2 fp32 -> fp8 (1728 blocks, exact) ----
        int q4 = (bid - 5248) * 256 + tid;
        int i = q4 * 4;
        int j = i;
        const float* src;
        if (j < NW_QKV) src = qkv;
        else if ((j -= NW_QKV) < NW_PROJ) src = proj;
        else if ((j -= NW_PROJ) < NW_FC1) src = fc1;
        else { j -= NW_FC1; src = fc2; }
        float4 v = *(const float4*)(src + j);
        int p = __builtin_amdgcn_cvt_pk_fp8_f32(v.x, v.y, 0, false);
        p = __builtin_amdgcn_cvt_pk_fp8_f32(v.z, v.w, p, true);
        *(int*)(w8 + i) = p;
    }
}

// ---------------- K2: prep1' (F = fc2@e2, 36 blocks, first) + qkv GEMM -------
__global__ __launch_bounds__(256) void gemm_qkv_prep(const unsigned char* __restrict__ hbuf8,
                                                     const unsigned char* __restrict__ wqkv8,
                                                     const float* __restrict__ qkv_b,
                                                     unsigned char* __restrict__ vtb8,
                                                     unsigned char* __restrict__ qk8,
                                                     const unsigned char* __restrict__ wfc28,
                                                     const unsigned char* __restrict__ e2t8,
                                                     unsigned char* __restrict__ wfe8) {
    __shared__ __attribute__((aligned(16))) unsigned char As[128 * 128];
    __shared__ __attribute__((aligned(16))) unsigned char Bs[128 * 128];
    int bid = blockIdx.x;
    if (bid < 36) {
        // F[384,1536] = fc2 @ e2 = A(wfc28) @ (e2^T)^T, K=1536
        gemm_core<0>(wfc28, e2t8, nullptr, nullptr, nullptr, nullptr, nullptr, wfe8,
                     1536, 1536, bid % 12, bid / 12, As, Bs);
    } else {
        int g = bid - 36;
        gemm_core<4>(hbuf8, wqkv8, qkv_b, nullptr, nullptr, nullptr, vtb8, qk8,
                     1152, 384, g % 9, g / 9, As, Bs);
    }
}

// ---------------- K4: proj GEMM + residual + ls1 + LayerNorm2 (pure) ---------
__global__ __launch_bounds__(256) void gemm_projln(const unsigned char* __restrict__ A,
                                                   const unsigned char* __restrict__ W,
                                                   const float* __restrict__ bias,
                                                   const float* __restrict__ resid,
                                                   const float* __restrict__ gamma,
                                                   const float* __restrict__ n2w,
                                                   const float* __restrict__ n2b,
                                                   float* __restrict__ x1,
                                                   unsigned char* __restrict__ hbuf8) {
    __shared__ __attribute__((aligned(16))) unsigned char As[64 * 128];
    __shared__ __attribute__((aligned(16))) unsigned char Bs[384 * 128];
    int tid = threadIdx.x;
    int wave = tid >> 6, lane = tid & 63;
    int l15 = lane & 15, quad = lane >> 4;
    int bm = blockIdx.x * 64;
    int wm = wave * 16;
    f32x4 acc[24];
#pragma unroll
    for (int i = 0; i < 24; i++) acc[i] = (f32x4){0.f, 0.f, 0.f, 0.f};

    const int K = 384;
    for (int k0 = 0; k0 < K; k0 += 128) {
#pragma unroll
        for (int i = 0; i < 2; i++) {
            int slot = i * 256 + tid;
            int rr = slot >> 3, gg = (slot & 7) ^ (rr & 7);
            GLOAD_LDS(A + (size_t)(bm + rr) * K + k0 + gg * 16, (char*)As + slot * 16);
        }
#pragma unroll
        for (int i = 0; i < 12; i++) {
            int slot = i * 256 + tid;
            int rr = slot >> 3, gg = (slot & 7) ^ (rr & 7);
            GLOAD_LDS(W + (size_t)rr * K + k0 + gg * 16, (char*)Bs + slot * 16);
        }
        __syncthreads();
        int rA = wm + l15;
        const i32x4* pa = (const i32x4*)(As + 128 * rA);
        i32x8 af = pack8(pa[(2 * quad) ^ (rA & 7)], pa[(2 * quad + 1) ^ (rA & 7)]);
#pragma unroll
        for (int nt = 0; nt < 24; nt++) {
            int rB = nt * 16 + l15;
            const i32x4* pb = (const i32x4*)(Bs + 128 * rB);
            i32x8 bf = pack8(pb[(2 * quad) ^ (rB & 7)], pb[(2 * quad + 1) ^ (rB & 7)]);
            acc[nt] = __builtin_amdgcn_mfma_scale_f32_16x16x128_f8f6f4(
                af, bf, acc[nt], 0, 0, 0, 0x7f7f7f7f, 0, 0x7f7f7f7f);
        }
        __syncthreads();
    }

    int row0 = bm + wm + quad * 4;
#pragma unroll
    for (int nt = 0; nt < 24; nt++) {
        int col = nt * 16 + l15;
        float bi = bias[col], ga = gamma[col];
#pragma unroll
        for (int r = 0; r < 4; r++) {
            size_t idx = (size_t)(row0 + r) * DIM + col;
            float v = resid[idx] + (acc[nt][r] + bi) * ga;
            x1[idx] = v;
            acc[nt][r] = v;
        }
    }
#pragma unroll
    for (int r = 0; r < 4; r++) {
        float s = 0.f;
#pragma unroll
        for (int nt = 0; nt < 24; nt++) s += acc[nt][r];
#pragma unroll
        for (int m = 1; m < 16; m <<= 1) s += __shfl_xor(s, m, 64);
        float mu = s * (1.f / DIM);
        float q = 0.f;
#pragma unroll
        for (int nt = 0; nt < 24; nt++) { float d = acc[nt][r] - mu; q += d * d; }
#pragma unroll
        for (int m = 1; m < 16; m <<= 1) q += __shfl_xor(q, m, 64);
        float rstd = rsqrtf(q * (1.f / DIM) + 1e-5f);
        unsigned char* orow = hbuf8 + (size_t)(row0 + r) * DIM;
#pragma unroll
        for (int nt = 0; nt < 24; nt++) {
            int col = nt * 16 + l15;
            orow[col] = to_fp8((acc[nt][r] - mu) * rstd * n2w[col] + n2b[col]);
        }
    }
}

// ---------------- attention core (KVBLK=128, fp8 32x32x64) -------------------
__device__ __forceinline__ void attn_core(const unsigned char* __restrict__ qk8,
                                          const unsigned char* __restrict__ vtb8,
                                          unsigned char* __restrict__ o,
                                          int bx, int bh, unsigned char* smem) {
    unsigned char* Ks0 = smem;                 // [128*64] x2
    unsigned char* Vts0 = smem + 2 * 128 * 64; // [64*128] x2
    int tid = threadIdx.x, wave = tid >> 6, lane = tid & 63;
    int l31 = lane & 31, h = lane >> 5;
    int b = bh / HEADS, hh = bh - b * HEADS;
    int qr0 = bx * 128 + wave * 32;
    const unsigned char* base = qk8 + (size_t)b * SEQ * 768;
    const unsigned char* vbase = vtb8 + ((size_t)bh << 17);  // bh*64*2048

    int kr0 = tid >> 2, kr1 = (tid + 256) >> 2, ks = tid & 3;
    const unsigned char* kg0 = base + (size_t)kr0 * 768 + 384 + hh * 64 + 16 * (ks ^ ((kr0 >> 1) & 3));
    const unsigned char* kg1 = base + (size_t)kr1 * 768 + 384 + hh * 64 + 16 * (ks ^ ((kr1 >> 1) & 3));
    int vr0 = tid >> 3, vr1 = (tid + 256) >> 3, vs = tid & 7;
    const unsigned char* vg0 = vbase + ((size_t)vr0 << 11) + 16 * (vs ^ ((vr0 >> 1) & 3));
    const unsigned char* vg1 = vbase + ((size_t)vr1 << 11) + 16 * (vs ^ ((vr1 >> 1) & 3));
    int lo0 = tid * 16, lo1 = (tid + 256) * 16;

    i32x8 aq = *(const i32x8*)(base + (size_t)(qr0 + l31) * 768 + hh * 64 + 32 * h);

    f32x16 oa0 = {}, oa1 = {};
    float lsum = 0.f;
    int swr = (l31 >> 1) & 3;

    GLOAD_LDS(kg0, (char*)Ks0 + lo0);
    GLOAD_LDS(kg1, (char*)Ks0 + lo1);
    GLOAD_LDS(vg0, (char*)Vts0 + lo0);
    GLOAD_LDS(vg1, (char*)Vts0 + lo1);
    __syncthreads();

    for (int kt = 0; kt < SEQ / 128; kt++) {
        const unsigned char* Kc = Ks0 + (kt & 1) * 128 * 64;
        const unsigned char* Vc = Vts0 + (kt & 1) * 64 * 128;
        if (kt + 1 < SEQ / 128) {
            char* kn = (char*)Ks0 + ((kt + 1) & 1) * 128 * 64;
            char* vn = (char*)Vts0 + ((kt + 1) & 1) * 64 * 128;
            size_t kadv = (size_t)(kt + 1) * 128 * 768;
            int vadv = (kt + 1) * 128;
            GLOAD_LDS(kg0 + kadv, kn + lo0);
            GLOAD_LDS(kg1 + kadv, kn + lo1);
            GLOAD_LDS(vg0 + vadv, vn + lo0);
            GLOAD_LDS(vg1 + vadv, vn + lo1);
        }

        int pk[4][4];
#pragma unroll
        for (int mi = 0; mi < 4; mi++) {
            int rK = 32 * mi + l31;
            const i32x4* kp = (const i32x4*)(Kc + rK * 64);
            i32x8 ak = pack8(kp[(2 * h + 0) ^ swr], kp[(2 * h + 1) ^ swr]);
            f32x16 s = {};
            s = __builtin_amdgcn_mfma_scale_f32_32x32x64_f8f6f4(
                ak, aq, s, 0, 0, 0, 0x7f7f7f7f, 0, 0x7f7f7f7f);
#pragma unroll
            for (int g = 0; g < 4; g++) {
                float p0 = __builtin_amdgcn_exp2f(s[4 * g + 0]);
                float p1 = __builtin_amdgcn_exp2f(s[4 * g + 1]);
                float p2 = __builtin_amdgcn_exp2f(s[4 * g + 2]);
                float p3 = __builtin_amdgcn_exp2f(s[4 * g + 3]);
                lsum += (p0 + p1) + (p2 + p3);
                int pkv = __builtin_amdgcn_cvt_pk_fp8_f32(p0, p1, 0, false);
                pkv = __builtin_amdgcn_cvt_pk_fp8_f32(p2, p3, pkv, true);
                pk[mi][g] = pkv;
            }
        }

        i32x8 ap0, ap1;
#pragma unroll
        for (int g = 0; g < 4; g++) {
            i32x2 r0 = __builtin_amdgcn_permlane32_swap(pk[0][g], pk[1][g], false, false);
            ap0[2 * g] = r0[0];
            ap0[2 * g + 1] = r0[1];
            i32x2 r1 = __builtin_amdgcn_permlane32_swap(pk[2][g], pk[3][g], false, false);
            ap1[2 * g] = r1[0];
            ap1[2 * g + 1] = r1[1];
        }

        {
            const i32x4* vp0 = (const i32x4*)(Vc + l31 * 128);
            const i32x4* vp1 = (const i32x4*)(Vc + (32 + l31) * 128);
            i32x8 bv00 = pack8(vp0[(2 * h + 0) ^ swr], vp0[(2 * h + 1) ^ swr]);
            i32x8 bv01 = pack8(vp0[4 + ((2 * h + 0) ^ swr)], vp0[4 + ((2 * h + 1) ^ swr)]);
            i32x8 bv10 = pack8(vp1[(2 * h + 0) ^ swr], vp1[(2 * h + 1) ^ swr]);
            i32x8 bv11 = pack8(vp1[4 + ((2 * h + 0) ^ swr)], vp1[4 + ((2 * h + 1) ^ swr)]);
            oa0 = __builtin_amdgcn_mfma_scale_f32_32x32x64_f8f6f4(
                ap0, bv00, oa0, 0, 0, 0, 0x7f7f7f7f, 0, 0x7f7f7f7f);
            oa0 = __builtin_amdgcn_mfma_scale_f32_32x32x64_f8f6f4(
                ap1, bv01, oa0, 0, 0, 0, 0x7f7f7f7f, 0, 0x7f7f7f7f);
            oa1 = __builtin_amdgcn_mfma_scale_f32_32x32x64_f8f6f4(
                ap0, bv10, oa1, 0, 0, 0, 0x7f7f7f7f, 0, 0x7f7f7f7f);
            oa1 = __builtin_amdgcn_mfma_scale_f32_32x32x64_f8f6f4(
                ap1, bv11, oa1, 0, 0, 0, 0x7f7f7f7f, 0, 0x7f7f7f7f);
        }
        __syncthreads();
    }

    lsum += __shfl_xor(lsum, 32, 64);

#pragma unroll
    for (int g = 0; g < 4; g++) {
#pragma unroll
        for (int r4 = 0; r4 < 4; r4++) {
            int qloc = r4 + 8 * g + 4 * h;
            float inv = 1.f / __shfl(lsum, qloc, 64);
            int r = 4 * g + r4;
            unsigned char* orow = o + ((size_t)(b * SEQ + qr0 + qloc)) * DIM + hh * 64;
            orow[l31]      = to_fp8(oa0[r] * inv);
            orow[32 + l31] = to_fp8(oa1[r] * inv);
        }
    }
}

// ---------------- K3: prep2' (Wc = F@e1, 36 blocks, first) + attention -------
__global__ __launch_bounds__(256) void attn_prep(const unsigned char* __restrict__ qk8,
                                                 const unsigned char* __restrict__ vtb8,
                                                 unsigned char* __restrict__ o,
                                                 const unsigned char* __restrict__ wfe8,
                                                 const unsigned char* __restrict__ e1t8,
                                                 unsigned char* __restrict__ wc8) {
    __shared__ __attribute__((aligned(16))) unsigned char smem[32768];
    int bid = blockIdx.x;
    if (bid < 36) {
        // Wc[384,1536] = F @ e1 = A(wfe8) @ (e1^T)^T, K=1536
        gemm_core<0>(wfe8, e1t8, nullptr, nullptr, nullptr, nullptr, nullptr, wc8,
                     1536, 1536, bid % 12, bid / 12, smem, smem + 128 * 128);
    } else {
        int g = bid - 36;
        attn_core(qk8, vtb8, o, g & 15, g >> 4, smem);
    }
}

// ---------------- orchestration ----------------------------------------------
extern "C" void kernel_launch(void* const* d_in, const int* in_sizes, int n_in,
                              void* d_out, int out_size, void* d_ws, size_t ws_size,
                              hipStream_t stream) {
    const float* x      = (const float*)d_in[0];
    const float* qkv_w  = (const float*)d_in[1];
    const float* qkv_b  = (const float*)d_in[2];
    const float* proj_w = (const float*)d_in[3];
    const float* proj_b = (const float*)d_in[4];
    const float* fc1_w  = (const float*)d_in[5];
    const float* fc1_b  = (const float*)d_in[6];
    const float* eye1_w = (const float*)d_in[7];
    const float* eye2_w = (const float*)d_in[8];
    const float* fc2_w  = (const float*)d_in[9];
    const float* fc2_b  = (const float*)d_in[10];
    const float* n1w    = (const float*)d_in[11];
    const float* n1b    = (const float*)d_in[12];
    const float* n2w    = (const float*)d_in[13];
    const float* n2b    = (const float*)d_in[14];
    const float* ls1    = (const float*)d_in[15];
    const float* ls2    = (const float*)d_in[16];
    float* out = (float*)d_out;

    char* w = (char*)d_ws;
    size_t off = 0;
    unsigned char* w8 = (unsigned char*)(w + off); off += (size_t)NW_ALL3;
    unsigned char* wqkv8  = w8;
    unsigned char* wproj8 = wqkv8 + NW_QKV;
    unsigned char* wfc18  = wproj8 + NW_PROJ;
    unsigned char* wfc28  = wfc18 + NW_FC1;
    unsigned char* e1t8  = (unsigned char*)(w + off); off += (size_t)NW_EYE;
    unsigned char* e2t8  = (unsigned char*)(w + off); off += (size_t)NW_EYE;
    unsigned char* wfe8  = (unsigned char*)(w + off); off += (size_t)NW_FC2;
    unsigned char* wc8   = (unsigned char*)(w + off); off += (size_t)NW_FC2;
    unsigned char* hbuf8 = (unsigned char*)(w + off); off += (size_t)TOKENS * DIM;
    unsigned char* qk8   = (unsigned char*)(w + off); off += (size_t)TOKENS * 768;
    unsigned char* vtb8  = (unsigned char*)(w + off); off += (size_t)TOKENS * DIM;
    unsigned char* obuf8 = (unsigned char*)(w + off); off += (size_t)TOKENS * DIM;
    unsigned char* abuf8 = (unsigned char*)(w + off); off += (size_t)TOKENS * HIDDEN;
    float* x1   = (float*)(w + off); off += (size_t)TOKENS * DIM * 4;

    // K1: ln1 + e1^T + e2^T + weight convert
    fused_pre<<<4096 + 1152 + 1728, 256, 0, stream>>>(
        x, n1w, n1b, hbuf8, eye1_w, e1t8, eye2_w, e2t8,
        qkv_w, proj_w, fc1_w, fc2_w, w8);

    // K2: prep1' (F = fc2@e2, 36 blocks) + qkv GEMM (1152 blocks)
    gemm_qkv_prep<<<36 + 1152, 256, 0, stream>>>(hbuf8, wqkv8, qkv_b, vtb8, qk8,
                                                 wfc28, e2t8, wfe8);

    // K3: prep2' (Wc = F@e1, 36 blocks) + attention (768 blocks, KVBLK=128)
    attn_prep<<<36 + 768, 256, 0, stream>>>(qk8, vtb8, obuf8, wfe8, e1t8, wc8);

    // K4: proj + resid + ls1 + LN2 (pure)
    gemm_projln<<<TOKENS / 64, 256, 0, stream>>>(obuf8, wproj8, proj_b, x, ls1,
                                                 n2w, n2b, x1, hbuf8);

    // K5: fc1 + GELU
    gemm_f8<2><<<dim3(1536 / 128, TOKENS / 128), 256, 0, stream>>>(
        hbuf8, wfc18, fc1_b, nullptr, nullptr, nullptr, nullptr, abuf8, 1536, 384);

    // K6: y = a @ Wc^T + bias; out = x1 + y*ls2  (BM=64: 768 blocks, 3/CU balanced)
    gemm_f8_m64<<<dim3(384 / 128, TOKENS / 64), 256, 0, stream>>>(
        abuf8, wc8, fc2_b, out, x1, ls2, 384, 1536);
}